// Round 6
// baseline (360.195 us; speedup 1.0000x reference)
//
#include <hip/hip_runtime.h>

#define KDIM 1024

typedef __attribute__((ext_vector_type(8))) short bf16x8;
typedef __attribute__((ext_vector_type(4))) short short4v;
typedef __attribute__((ext_vector_type(4))) float f32x4;
typedef __attribute__((ext_vector_type(2))) unsigned uint2v;

__device__ __forceinline__ short f2bf(float f) {
    union { float f; unsigned u; } x; x.f = f;
    unsigned r = x.u + 0x7fffu + ((x.u >> 16) & 1u);   // RNE
    return (short)(r >> 16);
}

__device__ __forceinline__ bf16x8 cvt8(f32x4 a, f32x4 b) {
    union { unsigned u[4]; bf16x8 v; } r;
    asm("v_cvt_pk_bf16_f32 %0, %1, %2" : "=v"(r.u[0]) : "v"(a.x), "v"(a.y));
    asm("v_cvt_pk_bf16_f32 %0, %1, %2" : "=v"(r.u[1]) : "v"(a.z), "v"(a.w));
    asm("v_cvt_pk_bf16_f32 %0, %1, %2" : "=v"(r.u[2]) : "v"(b.x), "v"(b.y));
    asm("v_cvt_pk_bf16_f32 %0, %1, %2" : "=v"(r.u[3]) : "v"(b.z), "v"(b.w));
    return r.v;
}

__device__ __forceinline__ void gload16(const void* g, void* l) {
    __builtin_amdgcn_global_load_lds(
        (const __attribute__((address_space(1))) void*)g,
        (__attribute__((address_space(3))) void*)l, 16, 0, 0);
}

#define WAIT_VM(n)  asm volatile("s_waitcnt vmcnt(" #n ")" ::: "memory")
#define WAIT_LGKM() asm volatile("s_waitcnt lgkmcnt(0)" ::: "memory")
#define BARRIER() do { asm volatile("" ::: "memory"); \
                       __builtin_amdgcn_s_barrier();  \
                       asm volatile("" ::: "memory"); } while (0)

// ---------------------------------------------------------------------------
// Decoder GEMM, sequential-W version.
// C[m][n] = sum_k A[m][k]*W[n][k] + bias[n]; M=256, K=1024.
// Block: N-panel of 256 W-rows (1 MB), 512 threads (8 waves), 196 blocks.
// The panel is consumed in 8 groups of 32 rows. Per group:
//   - 128 KB of W is read with PERFECTLY SEQUENTIAL coalesced loads
//     (wave-instr = 1 KB contiguous; panel walked linearly start to end),
//   - converted fp32->bf16 in-register (v_cvt_pk_bf16_f32),
//   - ds_written into a XOR-swizzled [32 rows][2KB] bf16 tile (64 KB),
//     double-buffered (2 x 64 KB LDS),
//   - then 32 k-frags MFMA'd: A-frags read DIRECTLY from global (A = 512 KB
//     bf16, L2-resident; 4 MB L2 traffic per block), B-frags from LDS.
// Loads for group g+2 are issued before the group-g barrier and waited with
// vmcnt(0) one full group later -> HBM latency fully hidden, stream never
// stalls on stride-thrashing (that was the 0.9 TB/s wall of R1-R5).
// Swizzle: 16B-chunk c of row rr stored at chunk (c ^ (rr&7)) ->
//   B-frag ds_read_b128: 16 lanes (rows) spread over 8 chunk-slots = 32 banks,
//   2 lanes/bank = free.
// ---------------------------------------------------------------------------
__launch_bounds__(512, 1)
__global__ void gemm_dec2(const short* __restrict__ A, const float* __restrict__ W,
                          float* __restrict__ C, const float* __restrict__ bias, int N)
{
    __shared__ __align__(1024) char lds[2][65536];

    const int n0 = blockIdx.x * 256;
    const int t = threadIdx.x;
    const int lane = t & 63;
    const int w = t >> 6;        // 0..7
    const int cl = lane & 15;
    const int kc = lane >> 4;    // 0..3

    f32x4 stg[16];               // one group's W share per thread (64 VGPR)

    // load j: u = w*16+j covers row rr = u>>2 (group-local), k-quarter q = u&3;
    // lane covers bytes q*1024 + lane*16 of that row -> 1 KB contiguous/instr.
    auto issue = [&](int g) {
        #pragma unroll
        for (int j = 0; j < 16; ++j) {
            const int u = w * 16 + j, rr = u >> 2, q = u & 3;
            int row = n0 + g * 32 + rr;
            row = (row < N) ? row : (N - 1);
            stg[j] = *(const f32x4*)(W + (size_t)row * KDIM + q * 256 + lane * 4);
        }
    };

    // cvt + swizzled ds_write_b64: bf16 chunk c = q*32 + (lane>>1), half = lane&1
    auto store_lds = [&](int slot) {
        char* base = lds[slot];
        #pragma unroll
        for (int j = 0; j < 16; ++j) {
            const int u = w * 16 + j, rr = u >> 2, q = u & 3;
            unsigned lo, hi;
            asm("v_cvt_pk_bf16_f32 %0, %1, %2" : "=v"(lo) : "v"(stg[j].x), "v"(stg[j].y));
            asm("v_cvt_pk_bf16_f32 %0, %1, %2" : "=v"(hi) : "v"(stg[j].z), "v"(stg[j].w));
            int c = q * 32 + (lane >> 1);
            int addr = rr * 2048 + ((c ^ (rr & 7)) << 4) + ((lane & 1) << 3);
            uint2v d; d.x = lo; d.y = hi;
            *(uint2v*)(base + addr) = d;
        }
    };

    f32x4 acc[2][2];

    // wave w owns m-frags {2w, 2w+1}; computes both 16-col n-frags of the group.
    auto compute = [&](int slot) {
        const char* base = lds[slot];
        const int sw = (cl & 7);
        const int rb0 = cl * 2048;              // row cl
        #pragma unroll
        for (int kf = 0; kf < 32; ++kf) {
            bf16x8 a0 = *(const bf16x8*)(A + (size_t)(((w * 2 + 0) * 32 + kf) * 64 + lane) * 8);
            bf16x8 a1 = *(const bf16x8*)(A + (size_t)(((w * 2 + 1) * 32 + kf) * 64 + lane) * 8);
            int boff = rb0 + (((kf * 4 + kc) ^ sw) << 4);
            bf16x8 b0 = *(const bf16x8*)(base + boff);            // rows 0..15
            bf16x8 b1 = *(const bf16x8*)(base + boff + 32768);    // rows 16..31
            acc[0][0] = __builtin_amdgcn_mfma_f32_16x16x32_bf16(a0, b0, acc[0][0], 0, 0, 0);
            acc[0][1] = __builtin_amdgcn_mfma_f32_16x16x32_bf16(a0, b1, acc[0][1], 0, 0, 0);
            acc[1][0] = __builtin_amdgcn_mfma_f32_16x16x32_bf16(a1, b0, acc[1][0], 0, 0, 0);
            acc[1][1] = __builtin_amdgcn_mfma_f32_16x16x32_bf16(a1, b1, acc[1][1], 0, 0, 0);
        }
    };

    auto cwrite = [&](int g) {
        #pragma unroll
        for (int m = 0; m < 2; ++m) {
            int row = (w * 2 + m) * 16 + kc * 4;
            #pragma unroll
            for (int nf = 0; nf < 2; ++nf) {
                int col = n0 + g * 32 + nf * 16 + cl;
                if (col < N) {
                    float bv = bias[col];
                    #pragma unroll
                    for (int r = 0; r < 4; ++r)
                        C[(size_t)(row + r) * N + col] = acc[m][nf][r] + bv;
                }
            }
        }
    };

    // prologue
    issue(0);
    WAIT_VM(0);
    store_lds(0);
    issue(1);                    // in flight through group 0's compute
    WAIT_LGKM();
    BARRIER();

    for (int g = 0; g < 8; ++g) {
        #pragma unroll
        for (int i = 0; i < 2; ++i)
            #pragma unroll
            for (int j = 0; j < 2; ++j)
                acc[i][j] = (f32x4){0.f, 0.f, 0.f, 0.f};

        compute(g & 1);
        if (g + 1 < 8) {
            WAIT_VM(0);                      // loads(g+1) landed (issued ~1 group ago)
            store_lds((g + 1) & 1);          // slot of g-1: consumed 2 barriers ago
            if (g + 2 < 8) issue(g + 2);     // pinned before barrier by "memory"
            WAIT_LGKM();
            BARRIER();
        }
        cwrite(g);
    }
}

// ---------------------------------------------------------------------------
// GRU gemm (R3 structure, proven, small & fast — weights L3-resident).
// ---------------------------------------------------------------------------
template<int NF, bool PRED>
__launch_bounds__(256, 2)
__global__ void gemm_pipe(const short* __restrict__ A0, const float* __restrict__ W0,
                          float* __restrict__ C0, int nb0,
                          const short* __restrict__ A1, const float* __restrict__ W1,
                          float* __restrict__ C1,
                          const float* __restrict__ bias, int N, int ldc)
{
    constexpr int WBYTES = NF * 4096;
    constexpr int BUFB   = 16384 + WBYTES;
    __shared__ __align__(1024) char lds[3 * BUFB];

    const int bx = blockIdx.x;
    const short* A; const float* W; float* C; int n0;
    if (bx < nb0) { A = A0; W = W0; C = C0; n0 = bx * (32 * NF); }
    else          { A = A1; W = W1; C = C1; n0 = (bx - nb0) * (32 * NF); }

    const int t = threadIdx.x;
    const int lane = t & 63;
    const int w = t >> 6;
    const int wr = w >> 1;
    const int wc = w & 1;

    const float* gW[NF];
    #pragma unroll
    for (int i = 0; i < NF; ++i) {
        int sl = (i * 4 + w) * 64 + lane;
        int row = sl >> 3, cc = sl & 7;
        int rowg = n0 + row;
        if (PRED) rowg = (rowg < N) ? rowg : (N - 1);
        gW[i] = W + (size_t)rowg * KDIM + ((cc ^ (row & 7)) << 2);
    }
    const short* gA[4];
    #pragma unroll
    for (int j = 0; j < 4; ++j)
        gA[j] = A + (size_t)(j * 4 + w) * 16384 + lane * 8;

    f32x4 acc[8][NF];
    #pragma unroll
    for (int i = 0; i < 8; ++i)
        #pragma unroll
        for (int j = 0; j < NF; ++j)
            acc[i][j] = (f32x4){0.f, 0.f, 0.f, 0.f};

    auto stage = [&](int s, int buf) {
        char* base = lds + buf * BUFB;
        #pragma unroll
        for (int i = 0; i < NF; ++i)
            gload16(gW[i] + s * 32, base + 16384 + (i * 4 + w) * 1024);
        #pragma unroll
        for (int j = 0; j < 4; ++j)
            gload16(gA[j] + s * 512, base + (j * 4 + w) * 1024);
    };

    auto compute = [&](int buf) {
        const char* base = lds + buf * BUFB;
        const char* Wb = base + 16384;
        bf16x8 bfr[NF];
        #pragma unroll
        for (int nf = 0; nf < NF; ++nf) {
            int row = (wc * NF + nf) * 16 + (lane & 15);
            int c0 = (lane >> 4) << 1;
            f32x4 lo = *(const f32x4*)(Wb + row * 128 + ((c0 ^ (row & 7)) << 4));
            f32x4 hi = *(const f32x4*)(Wb + row * 128 + (((c0 + 1) ^ (row & 7)) << 4));
            bfr[nf] = cvt8(lo, hi);
        }
        #pragma unroll
        for (int mf = 0; mf < 8; ++mf) {
            bf16x8 a = *(const bf16x8*)(base + (wr * 8 + mf) * 1024 + lane * 16);
            #pragma unroll
            for (int nf = 0; nf < NF; ++nf)
                acc[mf][nf] = __builtin_amdgcn_mfma_f32_16x16x32_bf16(a, bfr[nf], acc[mf][nf], 0, 0, 0);
        }
    };

    stage(0, 0);
    stage(1, 1);

    int bc = 0, bp = 2;
    for (int s = 0; s < 32; ++s) {
        if (s + 2 < 32) {
            stage(s + 2, bp);
            if constexpr (NF == 2) WAIT_VM(12); else WAIT_VM(10);
        } else if (s + 2 == 32) {
            if constexpr (NF == 2) WAIT_VM(6); else WAIT_VM(5);
        } else {
            WAIT_VM(0);
        }
        BARRIER();
        compute(bc);
        BARRIER();
        bc = (bc == 2) ? 0 : bc + 1;
        bp = (bp == 2) ? 0 : bp + 1;
    }

    #pragma unroll
    for (int mf = 0; mf < 8; ++mf) {
        int row = wr * 128 + mf * 16 + ((lane >> 4) << 2);
        #pragma unroll
        for (int nf = 0; nf < NF; ++nf) {
            int col = n0 + (wc * NF + nf) * 16 + (lane & 15);
            if (PRED && col >= N) continue;
            float bv = bias ? bias[col] : 0.0f;
            #pragma unroll
            for (int r = 0; r < 4; ++r)
                C[(size_t)(row + r) * ldc + col] = acc[mf][nf][r] + bv;
        }
    }
}

// Gather embedding row / convert hidden rows into bf16 fragment layout.
__global__ void prep_kernel(const int* __restrict__ ids, const float* __restrict__ hidden,
                            const float* __restrict__ emb,
                            short* __restrict__ x_frag, short* __restrict__ h_frag)
{
    const int m = blockIdx.x;
    const int which = blockIdx.y;
    const int j = threadIdx.x << 3;

    const float* src;
    short* dst;
    if (which == 0) { src = emb + (size_t)ids[m] * KDIM; dst = x_frag; }
    else {
        src = hidden + ((size_t)(which - 1) * 256 + m) * KDIM;
        dst = h_frag + (size_t)(which - 1) * 256 * KDIM;
    }
    f32x4 v0 = *(const f32x4*)(src + j);
    f32x4 v1 = *(const f32x4*)(src + j + 4);
    int mf = m >> 4, rr = m & 15, kf = j >> 5, g = (j >> 3) & 3;
    short* p = dst + (size_t)((mf * 32 + kf) * 64 + g * 16 + rr) * 8;
    short4v a, b;
    a.x = f2bf(v0.x); a.y = f2bf(v0.y); a.z = f2bf(v0.z); a.w = f2bf(v0.w);
    b.x = f2bf(v1.x); b.y = f2bf(v1.y); b.z = f2bf(v1.z); b.w = f2bf(v1.w);
    *(short4v*)p = a;
    *(short4v*)(p + 4) = b;
}

// GRU gates: h_new = (1-z)*n + z*h ; writes fp32 hidden_out and bf16 x fragments.
__global__ void gate_kernel(const float* __restrict__ gi, const float* __restrict__ gh,
                            const float* __restrict__ bi, const float* __restrict__ bh,
                            const float* __restrict__ hprev, float* __restrict__ hout,
                            short* __restrict__ x_frag)
{
    const int m = blockIdx.x;
    const int j = threadIdx.x << 3;
    const float* gim = gi + (size_t)m * 3072;
    const float* ghm = gh + (size_t)m * 3072;
    const float* hp = hprev + (size_t)m * KDIM;
    float* ho = hout + (size_t)m * KDIM;
    int mf = m >> 4, rr = m & 15, kf = j >> 5, g = (j >> 3) & 3;
    short* xp = x_frag + (size_t)((mf * 32 + kf) * 64 + g * 16 + rr) * 8;

    #pragma unroll
    for (int half = 0; half < 2; ++half) {
        int jj = j + half * 4;
        f32x4 vir = *(const f32x4*)(gim + jj);
        f32x4 viz = *(const f32x4*)(gim + 1024 + jj);
        f32x4 vin = *(const f32x4*)(gim + 2048 + jj);
        f32x4 vhr = *(const f32x4*)(ghm + jj);
        f32x4 vhz = *(const f32x4*)(ghm + 1024 + jj);
        f32x4 vhn = *(const f32x4*)(ghm + 2048 + jj);
        f32x4 bir = *(const f32x4*)(bi + jj);
        f32x4 biz = *(const f32x4*)(bi + 1024 + jj);
        f32x4 bin = *(const f32x4*)(bi + 2048 + jj);
        f32x4 bhr = *(const f32x4*)(bh + jj);
        f32x4 bhz = *(const f32x4*)(bh + 1024 + jj);
        f32x4 bhn = *(const f32x4*)(bh + 2048 + jj);
        f32x4 vh  = *(const f32x4*)(hp + jj);
        f32x4 outv;
        short4v xb;
        #pragma unroll
        for (int e = 0; e < 4; ++e) {
            float r = 1.f / (1.f + __expf(-(vir[e] + bir[e] + vhr[e] + bhr[e])));
            float z = 1.f / (1.f + __expf(-(viz[e] + biz[e] + vhz[e] + bhz[e])));
            float n = tanhf(vin[e] + bin[e] + r * (vhn[e] + bhn[e]));
            outv[e] = (1.f - z) * n + z * vh[e];
        }
        *(f32x4*)(ho + jj) = outv;
        xb.x = f2bf(outv[0]); xb.y = f2bf(outv[1]); xb.z = f2bf(outv[2]); xb.w = f2bf(outv[3]);
        *(short4v*)(xp + half * 4) = xb;
    }
}

extern "C" void kernel_launch(void* const* d_in, const int* in_sizes, int n_in,
                              void* d_out, int out_size, void* d_ws, size_t ws_size,
                              hipStream_t stream)
{
    const int*   ids    = (const int*)d_in[0];
    const float* hidden = (const float*)d_in[1];
    const float* emb    = (const float*)d_in[2];
    const float* w_ih   = (const float*)d_in[3];
    const float* w_hh   = (const float*)d_in[4];
    const float* b_ih   = (const float*)d_in[5];
    const float* b_hh   = (const float*)d_in[6];
    const float* dec_w  = (const float*)d_in[7];
    const float* dec_b  = (const float*)d_in[8];

    float* out = (float*)d_out;
    float* logits = out;                                  // [256][50000]
    float* hidden_out = out + (size_t)256 * 50000;        // [2][256][1024]

    short* x_frag = (short*)d_ws;                         // 256*1024 bf16
    short* h_frag = x_frag + 256 * 1024;                  // 2*256*1024 bf16
    float* gi = logits;                                   // scratch in logits region
    float* gh = logits + (size_t)256 * 3072;

    prep_kernel<<<dim3(256, 3), 128, 0, stream>>>(ids, hidden, emb, x_frag, h_frag);

    for (int l = 0; l < 2; ++l) {
        gemm_pipe<1, false><<<192, 256, 0, stream>>>(
            x_frag, w_ih + (size_t)l * 3072 * 1024, gi, 96,
            h_frag + (size_t)l * 256 * 1024, w_hh + (size_t)l * 3072 * 1024, gh,
            nullptr, 3072, 3072);
        gate_kernel<<<256, 128, 0, stream>>>(
            gi, gh, b_ih + (size_t)l * 3072, b_hh + (size_t)l * 3072,
            hidden + (size_t)l * 256 * 1024,
            hidden_out + (size_t)l * 256 * 1024, x_frag);
    }

    // decoder: sequential-W streaming, 256-col panels, 196 blocks, 8 waves
    gemm_dec2<<<196, 512, 0, stream>>>(x_frag, dec_w, logits, dec_b, 50000);
}

// Round 7
// 126.064 us; speedup vs baseline: 2.8572x; 2.8572x over previous
//
#include <hip/hip_runtime.h>

#define KDIM 1024

typedef __attribute__((ext_vector_type(8))) short bf16x8;
typedef __attribute__((ext_vector_type(4))) short short4v;
typedef __attribute__((ext_vector_type(4))) float f32x4;

__device__ __forceinline__ short f2bf(float f) {
    union { float f; unsigned u; } x; x.f = f;
    unsigned r = x.u + 0x7fffu + ((x.u >> 16) & 1u);   // RNE
    return (short)(r >> 16);
}

__device__ __forceinline__ bf16x8 cvt8(f32x4 a, f32x4 b) {
    union { unsigned u[4]; bf16x8 v; } r;
    asm("v_cvt_pk_bf16_f32 %0, %1, %2" : "=v"(r.u[0]) : "v"(a.x), "v"(a.y));
    asm("v_cvt_pk_bf16_f32 %0, %1, %2" : "=v"(r.u[1]) : "v"(a.z), "v"(a.w));
    asm("v_cvt_pk_bf16_f32 %0, %1, %2" : "=v"(r.u[2]) : "v"(b.x), "v"(b.y));
    asm("v_cvt_pk_bf16_f32 %0, %1, %2" : "=v"(r.u[3]) : "v"(b.z), "v"(b.w));
    return r.v;
}

__device__ __forceinline__ void gload16(const void* g, void* l) {
    __builtin_amdgcn_global_load_lds(
        (const __attribute__((address_space(1))) void*)g,
        (__attribute__((address_space(3))) void*)l, 16, 0, 0);
}

#define WAIT_VM(n)  asm volatile("s_waitcnt vmcnt(" #n ")" ::: "memory")
#define BARRIER() do { asm volatile("" ::: "memory"); \
                       __builtin_amdgcn_s_barrier();  \
                       asm volatile("" ::: "memory"); } while (0)

// ---------------------------------------------------------------------------
// Decoder GEMM v3: C[m][n] = sum_k A[m][k]*W[n][k] + bias[n]; M=256, K=1024.
// 392 blocks x 512 thr (8 waves). Per block: N-tile 128. Group = 32 rows x
// 256-float K-quarter = 32 KB fp32 in LDS; 16 groups (rg 0..3 x kq 0..3).
// W staging: global_load_lds, one instr = ONE FULL 1-KB contiguous row-quarter
// (lane-permuted within the 1 KB window for bank swizzle; same involution on
// read). No registers consumed -> no spill (R6's failure). 2-buffer, stage
// g+2 after compute g (~1.5 iters in flight). WAIT_VM(4) uniform (leaves only
// the newest stage outstanding; robust to vmcnt accounting of A-loads/stores).
// A: bf16 pre-fragmented, read directly from global (L2-resident, per-wave
// exclusive m-frags -> 2 MB/block, 784 MB aggregate). acc[2][2] per wave.
// LDS 64 KB/block -> 2 blocks/CU (16 waves/CU).
// ---------------------------------------------------------------------------
__launch_bounds__(512, 4)
__global__ void gemm_dec3(const short* __restrict__ A, const float* __restrict__ W,
                          float* __restrict__ C, const float* __restrict__ bias, int N)
{
    __shared__ __align__(1024) char lds[2][32768];

    const int n0 = blockIdx.x * 128;
    const int t = threadIdx.x;
    const int lane = t & 63;
    const int w = t >> 6;        // 0..7
    const int cl = lane & 15;
    const int kc = lane >> 4;    // 0..3

    // lane permutation for the 4 staging instrs (rr = w*4+i)
    int perm[4];
    #pragma unroll
    for (int i = 0; i < 4; ++i) {
        int rr = w * 4 + i;
        perm[i] = (lane & ~7) | ((lane & 7) ^ (rr & 7));
    }

    // bias preload: 4 rg x 2 nf values per lane
    float bv[4][2];
    #pragma unroll
    for (int rg = 0; rg < 4; ++rg)
        #pragma unroll
        for (int nf = 0; nf < 2; ++nf) {
            int col = n0 + rg * 32 + nf * 16 + cl;
            bv[rg][nf] = bias[col < N ? col : 0];
        }

    auto stage = [&](int g) {
        const int rg = g >> 2, kq = g & 3;
        char* base = lds[g & 1];
        #pragma unroll
        for (int i = 0; i < 4; ++i) {
            int rr = w * 4 + i;
            int rowg = n0 + rg * 32 + rr;
            rowg = (rowg < N) ? rowg : (N - 1);
            gload16(W + (size_t)rowg * KDIM + kq * 256 + perm[i] * 4,
                    base + rr * 1024);
        }
    };

    f32x4 acc[2][2];

    auto compute = [&](int g) {
        const int kq = g & 3;
        const char* r0 = lds[g & 1] + cl * 1024;
        const int s = cl & 7;
        #pragma unroll
        for (int kf = 0; kf < 8; ++kf) {
            const int kfg = kq * 8 + kf;
            bf16x8 a0 = *(const bf16x8*)(A + (size_t)((w * 2 + 0) * 32 + kfg) * 512 + lane * 8);
            bf16x8 a1 = *(const bf16x8*)(A + (size_t)((w * 2 + 1) * 32 + kfg) * 512 + lane * 8);
            const int qlo = kf * 8 + ((kc * 2) ^ s);
            const int qhi = kf * 8 + ((kc * 2 + 1) ^ s);
            f32x4 lo0 = *(const f32x4*)(r0 + qlo * 16);
            f32x4 hi0 = *(const f32x4*)(r0 + qhi * 16);
            f32x4 lo1 = *(const f32x4*)(r0 + 16384 + qlo * 16);
            f32x4 hi1 = *(const f32x4*)(r0 + 16384 + qhi * 16);
            bf16x8 b0 = cvt8(lo0, hi0);
            bf16x8 b1 = cvt8(lo1, hi1);
            acc[0][0] = __builtin_amdgcn_mfma_f32_16x16x32_bf16(a0, b0, acc[0][0], 0, 0, 0);
            acc[0][1] = __builtin_amdgcn_mfma_f32_16x16x32_bf16(a0, b1, acc[0][1], 0, 0, 0);
            acc[1][0] = __builtin_amdgcn_mfma_f32_16x16x32_bf16(a1, b0, acc[1][0], 0, 0, 0);
            acc[1][1] = __builtin_amdgcn_mfma_f32_16x16x32_bf16(a1, b1, acc[1][1], 0, 0, 0);
        }
    };

    stage(0);
    stage(1);

    for (int g = 0; g < 16; ++g) {
        WAIT_VM(4);              // everything except the newest stage has landed
        BARRIER();               // stage(g) visible to all waves
        if ((g & 3) == 0) {
            #pragma unroll
            for (int i = 0; i < 2; ++i)
                #pragma unroll
                for (int j = 0; j < 2; ++j)
                    acc[i][j] = (f32x4){0.f, 0.f, 0.f, 0.f};
        }
        compute(g);
        BARRIER();               // buf (g&1) fully read
        if (g + 2 < 16) stage(g + 2);
        if ((g & 3) == 3) {
            const int rg = g >> 2;
            #pragma unroll
            for (int m = 0; m < 2; ++m) {
                int row = (w * 2 + m) * 16 + kc * 4;
                #pragma unroll
                for (int nf = 0; nf < 2; ++nf) {
                    int col = n0 + rg * 32 + nf * 16 + cl;
                    if (col < N) {
                        #pragma unroll
                        for (int r = 0; r < 4; ++r)
                            C[(size_t)(row + r) * N + col] = acc[m][nf][r] + bv[rg][nf];
                    }
                }
            }
        }
    }
}

// ---------------------------------------------------------------------------
// GRU gemm (R3 structure, proven; weights L3-resident).
// ---------------------------------------------------------------------------
template<int NF, bool PRED>
__launch_bounds__(256, 2)
__global__ void gemm_pipe(const short* __restrict__ A0, const float* __restrict__ W0,
                          float* __restrict__ C0, int nb0,
                          const short* __restrict__ A1, const float* __restrict__ W1,
                          float* __restrict__ C1,
                          const float* __restrict__ bias, int N, int ldc)
{
    constexpr int WBYTES = NF * 4096;
    constexpr int BUFB   = 16384 + WBYTES;
    __shared__ __align__(1024) char lds[3 * BUFB];

    const int bx = blockIdx.x;
    const short* A; const float* W; float* C; int n0;
    if (bx < nb0) { A = A0; W = W0; C = C0; n0 = bx * (32 * NF); }
    else          { A = A1; W = W1; C = C1; n0 = (bx - nb0) * (32 * NF); }

    const int t = threadIdx.x;
    const int lane = t & 63;
    const int w = t >> 6;
    const int wr = w >> 1;
    const int wc = w & 1;

    const float* gW[NF];
    #pragma unroll
    for (int i = 0; i < NF; ++i) {
        int sl = (i * 4 + w) * 64 + lane;
        int row = sl >> 3, cc = sl & 7;
        int rowg = n0 + row;
        if (PRED) rowg = (rowg < N) ? rowg : (N - 1);
        gW[i] = W + (size_t)rowg * KDIM + ((cc ^ (row & 7)) << 2);
    }
    const short* gA[4];
    #pragma unroll
    for (int j = 0; j < 4; ++j)
        gA[j] = A + (size_t)(j * 4 + w) * 16384 + lane * 8;

    f32x4 acc[8][NF];
    #pragma unroll
    for (int i = 0; i < 8; ++i)
        #pragma unroll
        for (int j = 0; j < NF; ++j)
            acc[i][j] = (f32x4){0.f, 0.f, 0.f, 0.f};

    auto stage = [&](int s, int buf) {
        char* base = lds + buf * BUFB;
        #pragma unroll
        for (int i = 0; i < NF; ++i)
            gload16(gW[i] + s * 32, base + 16384 + (i * 4 + w) * 1024);
        #pragma unroll
        for (int j = 0; j < 4; ++j)
            gload16(gA[j] + s * 512, base + (j * 4 + w) * 1024);
    };

    auto compute = [&](int buf) {
        const char* base = lds + buf * BUFB;
        const char* Wb = base + 16384;
        bf16x8 bfr[NF];
        #pragma unroll
        for (int nf = 0; nf < NF; ++nf) {
            int row = (wc * NF + nf) * 16 + (lane & 15);
            int c0 = (lane >> 4) << 1;
            f32x4 lo = *(const f32x4*)(Wb + row * 128 + ((c0 ^ (row & 7)) << 4));
            f32x4 hi = *(const f32x4*)(Wb + row * 128 + (((c0 + 1) ^ (row & 7)) << 4));
            bfr[nf] = cvt8(lo, hi);
        }
        #pragma unroll
        for (int mf = 0; mf < 8; ++mf) {
            bf16x8 a = *(const bf16x8*)(base + (wr * 8 + mf) * 1024 + lane * 16);
            #pragma unroll
            for (int nf = 0; nf < NF; ++nf)
                acc[mf][nf] = __builtin_amdgcn_mfma_f32_16x16x32_bf16(a, bfr[nf], acc[mf][nf], 0, 0, 0);
        }
    };

    stage(0, 0);
    stage(1, 1);

    int bc = 0, bp = 2;
    for (int s = 0; s < 32; ++s) {
        if (s + 2 < 32) {
            stage(s + 2, bp);
            if constexpr (NF == 2) WAIT_VM(12); else WAIT_VM(10);
        } else if (s + 2 == 32) {
            if constexpr (NF == 2) WAIT_VM(6); else WAIT_VM(5);
        } else {
            WAIT_VM(0);
        }
        BARRIER();
        compute(bc);
        BARRIER();
        bc = (bc == 2) ? 0 : bc + 1;
        bp = (bp == 2) ? 0 : bp + 1;
    }

    #pragma unroll
    for (int mf = 0; mf < 8; ++mf) {
        int row = wr * 128 + mf * 16 + ((lane >> 4) << 2);
        #pragma unroll
        for (int nf = 0; nf < NF; ++nf) {
            int col = n0 + (wc * NF + nf) * 16 + (lane & 15);
            if (PRED && col >= N) continue;
            float bvv = bias ? bias[col] : 0.0f;
            #pragma unroll
            for (int r = 0; r < 4; ++r)
                C[(size_t)(row + r) * ldc + col] = acc[mf][nf][r] + bvv;
        }
    }
}

// Gather embedding row / convert hidden rows into bf16 fragment layout.
__global__ void prep_kernel(const int* __restrict__ ids, const float* __restrict__ hidden,
                            const float* __restrict__ emb,
                            short* __restrict__ x_frag, short* __restrict__ h_frag)
{
    const int m = blockIdx.x;
    const int which = blockIdx.y;
    const int j = threadIdx.x << 3;

    const float* src;
    short* dst;
    if (which == 0) { src = emb + (size_t)ids[m] * KDIM; dst = x_frag; }
    else {
        src = hidden + ((size_t)(which - 1) * 256 + m) * KDIM;
        dst = h_frag + (size_t)(which - 1) * 256 * KDIM;
    }
    f32x4 v0 = *(const f32x4*)(src + j);
    f32x4 v1 = *(const f32x4*)(src + j + 4);
    int mf = m >> 4, rr = m & 15, kf = j >> 5, g = (j >> 3) & 3;
    short* p = dst + (size_t)((mf * 32 + kf) * 64 + g * 16 + rr) * 8;
    short4v a, b;
    a.x = f2bf(v0.x); a.y = f2bf(v0.y); a.z = f2bf(v0.z); a.w = f2bf(v0.w);
    b.x = f2bf(v1.x); b.y = f2bf(v1.y); b.z = f2bf(v1.z); b.w = f2bf(v1.w);
    *(short4v*)p = a;
    *(short4v*)(p + 4) = b;
}

// GRU gates: h_new = (1-z)*n + z*h ; writes fp32 hidden_out and bf16 x fragments.
__global__ void gate_kernel(const float* __restrict__ gi, const float* __restrict__ gh,
                            const float* __restrict__ bi, const float* __restrict__ bh,
                            const float* __restrict__ hprev, float* __restrict__ hout,
                            short* __restrict__ x_frag)
{
    const int m = blockIdx.x;
    const int j = threadIdx.x << 3;
    const float* gim = gi + (size_t)m * 3072;
    const float* ghm = gh + (size_t)m * 3072;
    const float* hp = hprev + (size_t)m * KDIM;
    float* ho = hout + (size_t)m * KDIM;
    int mf = m >> 4, rr = m & 15, kf = j >> 5, g = (j >> 3) & 3;
    short* xp = x_frag + (size_t)((mf * 32 + kf) * 64 + g * 16 + rr) * 8;

    #pragma unroll
    for (int half = 0; half < 2; ++half) {
        int jj = j + half * 4;
        f32x4 vir = *(const f32x4*)(gim + jj);
        f32x4 viz = *(const f32x4*)(gim + 1024 + jj);
        f32x4 vin = *(const f32x4*)(gim + 2048 + jj);
        f32x4 vhr = *(const f32x4*)(ghm + jj);
        f32x4 vhz = *(const f32x4*)(ghm + 1024 + jj);
        f32x4 vhn = *(const f32x4*)(ghm + 2048 + jj);
        f32x4 bir = *(const f32x4*)(bi + jj);
        f32x4 biz = *(const f32x4*)(bi + 1024 + jj);
        f32x4 bin = *(const f32x4*)(bi + 2048 + jj);
        f32x4 bhr = *(const f32x4*)(bh + jj);
        f32x4 bhz = *(const f32x4*)(bh + 1024 + jj);
        f32x4 bhn = *(const f32x4*)(bh + 2048 + jj);
        f32x4 vh  = *(const f32x4*)(hp + jj);
        f32x4 outv;
        short4v xb;
        #pragma unroll
        for (int e = 0; e < 4; ++e) {
            float r = 1.f / (1.f + __expf(-(vir[e] + bir[e] + vhr[e] + bhr[e])));
            float z = 1.f / (1.f + __expf(-(viz[e] + biz[e] + vhz[e] + bhz[e])));
            float n = tanhf(vin[e] + bin[e] + r * (vhn[e] + bhn[e]));
            outv[e] = (1.f - z) * n + z * vh[e];
        }
        *(f32x4*)(ho + jj) = outv;
        xb.x = f2bf(outv[0]); xb.y = f2bf(outv[1]); xb.z = f2bf(outv[2]); xb.w = f2bf(outv[3]);
        *(short4v*)(xp + half * 4) = xb;
    }
}

extern "C" void kernel_launch(void* const* d_in, const int* in_sizes, int n_in,
                              void* d_out, int out_size, void* d_ws, size_t ws_size,
                              hipStream_t stream)
{
    const int*   ids    = (const int*)d_in[0];
    const float* hidden = (const float*)d_in[1];
    const float* emb    = (const float*)d_in[2];
    const float* w_ih   = (const float*)d_in[3];
    const float* w_hh   = (const float*)d_in[4];
    const float* b_ih   = (const float*)d_in[5];
    const float* b_hh   = (const float*)d_in[6];
    const float* dec_w  = (const float*)d_in[7];
    const float* dec_b  = (const float*)d_in[8];

    float* out = (float*)d_out;
    float* logits = out;                                  // [256][50000]
    float* hidden_out = out + (size_t)256 * 50000;        // [2][256][1024]

    short* x_frag = (short*)d_ws;                         // 256*1024 bf16
    short* h_frag = x_frag + 256 * 1024;                  // 2*256*1024 bf16
    float* gi = logits;                                   // scratch in logits region
    float* gh = logits + (size_t)256 * 3072;

    prep_kernel<<<dim3(256, 3), 128, 0, stream>>>(ids, hidden, emb, x_frag, h_frag);

    for (int l = 0; l < 2; ++l) {
        gemm_pipe<1, false><<<192, 256, 0, stream>>>(
            x_frag, w_ih + (size_t)l * 3072 * 1024, gi, 96,
            h_frag + (size_t)l * 256 * 1024, w_hh + (size_t)l * 3072 * 1024, gh,
            nullptr, 3072, 3072);
        gate_kernel<<<256, 128, 0, stream>>>(
            gi, gh, b_ih + (size_t)l * 3072, b_hh + (size_t)l * 3072,
            hidden + (size_t)l * 256 * 1024,
            hidden_out + (size_t)l * 256 * 1024, x_frag);
    }

    // decoder: sequential row-quarter DMA streaming, N-tile 128, 392 blocks
    gemm_dec3<<<392, 512, 0, stream>>>(x_frag, dec_w, logits, dec_b, 50000);
}